// Round 2
// baseline (241.207 us; speedup 1.0000x reference)
//
#include <hip/hip_runtime.h>

// ActiveBoundaryLoss on MI355X.
// Inputs: d_in[0]=slices f32 (4,19,512,512), d_in[1]=dist_maps f32 (4,1,512,512),
//         d_in[2]=targets i32 (4,1,512,512). Output: 1 float scalar.

#define NCLS 19
#define BB 4
#define HH 512
#define WW 512
#define HWC (HH*WW)            // 262144 = 2^18
#define CHW (NCLS*HWC)
#define NPIX (BB*HWC)          // 1048576
#define NEPS 256
#define MAXDIS 100000.0f
#define LIST_CAP 32768
// count threshold: while sum(klc>eps) > 512*512*0.01 (=2621.44) -> continue if count>=2622
#define CNT_THRESH 2621u

// ws byte offsets
#define O_LSE   0u
#define O_KLC   4194304u
#define O_TL    8388608u           // double tl_part[4096]
#define O_CNT   8421376u           // uint cnt_part[1024]
#define O_HIST  8425472u           // uint hist[257]
#define O_LISTN 8426500u           // uint list_n
// pad 8 bytes -> 8426512
#define O_SUMS  8426512u           // double sum_lsce, sum_w
#define O_EPS   8426528u           // float eps_final
#define O_LIST  8426532u           // int list[LIST_CAP]
#define MEMSET_OFF O_HIST
#define MEMSET_LEN 1056u           // hist(1028)+listn(4)+pad(8)+sums(16)

// ---------------- Kernel A: lse per pixel + target CE partial sums ----------
__global__ void kA_lse_ce(const float* __restrict__ x, const int* __restrict__ tgt,
                          float* __restrict__ lse, double* __restrict__ tl_part) {
  int tid = threadIdx.x;
  int p = blockIdx.x * 256 + tid;
  int b = p >> 18;
  int hw = p & (HWC - 1);
  const float* xp = x + (size_t)b * CHW + hw;

  float v[NCLS];
  float m = -1e30f;
#pragma unroll
  for (int c = 0; c < NCLS; c++) {
    v[c] = xp[(size_t)c * HWC];
    m = fmaxf(m, v[c]);
  }
  float s = 0.f;
#pragma unroll
  for (int c = 0; c < NCLS; c++) s += __expf(v[c] - m);
  float l = m + __logf(s);
  lse[p] = l;

  int t = tgt[p];
  float ce = 0.f;
  if (t != 255) {
    // select v[t] without runtime indexing (avoids scratch)
    float xt = v[0];
#pragma unroll
    for (int c = 1; c < NCLS; c++) xt = (t == c) ? v[c] : xt;
    ce = l - xt;   // -(x[t]-lse)
  }

  __shared__ float red[256];
  red[tid] = ce;
  __syncthreads();
  for (int o = 128; o > 0; o >>= 1) {
    if (tid < o) red[tid] += red[tid + o];
    __syncthreads();
  }
  if (tid == 0) tl_part[blockIdx.x] = (double)red[0];
}

// ---------------- Kernel B: klc per pixel + eps histogram -------------------
__global__ void kB_klc(const float* __restrict__ x, const float* __restrict__ lse,
                       float* __restrict__ klc, unsigned int* __restrict__ hist) {
  __shared__ float eps[NEPS];
  __shared__ unsigned int lh[NEPS + 1];
  int tid = threadIdx.x;
  for (int i = tid; i < NEPS + 1; i += 256) lh[i] = 0u;
  if (tid == 0) {
    float e = 1e-5f;
    for (int i = 0; i < NEPS; i++) { eps[i] = e; e *= 1.2f; }  // exact fp32 sequence
  }
  __syncthreads();

  int p = blockIdx.x * 256 + tid;
  int b = p >> 18;
  int hw = p & (HWC - 1);
  int h = hw >> 9;
  int w = hw & 511;
  const float* xp = x + (size_t)b * CHW + hw;
  float lc = lse[p];
  bool hasD = (h < HH - 1), hasR = (w < WW - 1);
  int offD = hasD ? WW : 0;
  int offR = hasR ? 1 : 0;
  float ld = lse[p + offD];
  float lr = lse[p + offR];

  float sD = 0.f, sR = 0.f;
#pragma unroll
  for (int c = 0; c < NCLS; c++) {
    float xc = xp[(size_t)c * HWC];
    float lmc = xc - lc;
    float pc = __expf(lmc);
    float xd = xp[(size_t)c * HWC + offD];
    float xr = xp[(size_t)c * HWC + offR];
    sD += pc * (lmc - (xd - ld));
    sR += pc * (lmc - (xr - lr));
  }
  float kv = (hasD ? sD : 0.f) + (hasR ? sR : 0.f);
  klc[p] = kv;

  // idx = number of eps entries strictly below kv (kv > eps[j])
  int lo = 0, hi = NEPS;
  while (lo < hi) {
    int mid = (lo + hi) >> 1;
    if (kv > eps[mid]) lo = mid + 1; else hi = mid;
  }
  atomicAdd(&lh[lo], 1u);
  __syncthreads();
  for (int i = tid; i < NEPS + 1; i += 256)
    if (lh[i]) atomicAdd(&hist[i], lh[i]);
}

// ---------------- Kernel C: find final eps ---------------------------------
__global__ void kC_eps(const unsigned int* __restrict__ hist, float* __restrict__ eps_final) {
  if (threadIdx.x == 0) {
    unsigned int cnt = 0;              // count_0 = sum_{i>=1} hist[i]
    for (int i = 1; i <= NEPS; i++) cnt += hist[i];
    int K = 0;
    while (cnt > CNT_THRESH && K < NEPS - 1) {
      K++;
      cnt -= hist[K];                  // count_K = count_{K-1} - hist[K]
    }
    float e = 1e-5f;
    for (int i = 0; i < K; i++) e *= 1.2f;
    *eps_final = e;
  }
}

// ---------------- Kernel D1: dilated mask -> compacted pixel list ----------
__global__ void kD1_compact(const float* __restrict__ klc, const float* __restrict__ epsp,
                            int* __restrict__ list, unsigned int* __restrict__ list_n,
                            unsigned int* __restrict__ cnt_part) {
  __shared__ unsigned int lcnt, lbase;
  __shared__ int lbuf[1024];
  int tid = threadIdx.x;
  if (tid == 0) lcnt = 0u;
  __syncthreads();
  float eps = *epsp;
  int base = blockIdx.x * 1024;
#pragma unroll
  for (int k = 0; k < 4; k++) {
    int p = base + k * 256 + tid;
    int b = p >> 18;
    int hw = p & (HWC - 1);
    int h = hw >> 9;
    int w = hw & 511;
    const float* kb = klc + b * HWC;
    bool pb = false;
#pragma unroll
    for (int dh = -1; dh <= 1; dh++)
#pragma unroll
      for (int dw = -1; dw <= 1; dw++) {
        int hh = h + dh, wn = w + dw;
        if (hh >= 0 && hh < HH && wn >= 0 && wn < WW)
          pb = pb || (kb[hh * WW + wn] > eps);
      }
    if (pb) {
      unsigned int idx = atomicAdd(&lcnt, 1u);
      lbuf[idx] = p;
    }
  }
  __syncthreads();
  if (tid == 0) {
    unsigned int c = lcnt;
    lbase = c ? atomicAdd(list_n, c) : 0u;
    cnt_part[blockIdx.x] = c;
  }
  __syncthreads();
  unsigned int c = lcnt, bo = lbase;
  for (unsigned int j = tid; j < c; j += 256) {
    unsigned int dst = bo + j;
    if (dst < LIST_CAP) list[dst] = lbuf[j];
  }
}

// ---------------- Kernel D2: heavy path on compacted pixels ----------------
__global__ void kD2_border(const float* __restrict__ x, const float* __restrict__ lse,
                           const float* __restrict__ dist, const int* __restrict__ list,
                           const unsigned int* __restrict__ list_n,
                           double* __restrict__ sums /* [0]=lsce [1]=w */) {
  const int DXc[9] = {1, -1, 0, 0, -1, 1, -1, 1, 0};
  const int DYc[9] = {0, 0, -1, 1, 1, 1, -1, -1, 0};
  int i = blockIdx.x * 256 + threadIdx.x;
  unsigned int n = *list_n;
  if (n > LIST_CAP) n = LIST_CAP;
  float lsce = 0.f, wv = 0.f;
  if (i < (int)n) {
    int p = list[i];
    int b = p >> 18;
    int hw = p & (HWC - 1);
    int h = hw >> 9;
    int w = hw & 511;
    const float* db = dist + b * HWC;
    float dmin = 0.f, d8c = 0.f;
    int g = 0;
#pragma unroll
    for (int k = 0; k < 9; k++) {
      int hh = h + DXc[k], wn = w + DYc[k];
      float d = (hh >= 0 && hh < HH && wn >= 0 && wn < WW) ? db[hh * WW + wn] : MAXDIS;
      if (k == 0) { dmin = d; }
      else if (d < dmin) { dmin = d; g = k; }   // first-min-wins, matches jnp.argmin
      if (k == 8) d8c = d;                      // center dist, always in bounds
    }
    if (g != 8) {   // valid
      const float* xp = x + (size_t)b * CHW;
      float lc = lse[p];
      float xc[NCLS];
#pragma unroll
      for (int c = 0; c < NCLS; c++) xc[c] = xp[(size_t)c * HWC + hw];
      float kl8[8];
#pragma unroll
      for (int k = 0; k < 8; k++) {
        int hh = min(max(h + DXc[k], 0), HH - 1);   // edge padding
        int wn = min(max(w + DYc[k], 0), WW - 1);
        int hwn = hh * WW + wn;
        float ln = lse[b * HWC + hwn];
        float s = 0.f;
#pragma unroll
        for (int c = 0; c < NCLS; c++) {
          float xn = xp[(size_t)c * HWC + hwn];
          float lsn = xn - ln;
          s += __expf(lsn) * (lsn - (xc[c] - lc));   // KL(neighbor || center)
        }
        kl8[k] = s;
      }
      float m8 = kl8[0];
#pragma unroll
      for (int k = 1; k < 8; k++) m8 = fmaxf(m8, kl8[k]);
      float se = 0.f;
#pragma unroll
      for (int k = 0; k < 8; k++) se += __expf(kl8[k] - m8);
      float l8 = m8 + __logf(se);
      float sum_lq = 0.f, lq_g = 0.f;
#pragma unroll
      for (int k = 0; k < 8; k++) {
        float lq = kl8[k] - l8;
        sum_lq += lq;
        if (k == g) lq_g = lq;
      }
      // smooth labels: 0.8 at g, 0.025 elsewhere => lsce = -(0.025*sum + 0.775*lq_g)
      lsce = -(0.025f * sum_lq + 0.775f * lq_g);
      wv = fminf(d8c, 20.0f) * (1.0f / 20.0f);
    }
  }
  // wave-level reduce, one double atomic per wave per quantity
  float rl = lsce, rw = wv;
#pragma unroll
  for (int o = 32; o > 0; o >>= 1) {
    rl += __shfl_xor(rl, o);
    rw += __shfl_xor(rw, o);
  }
  if ((threadIdx.x & 63) == 0 && (rl != 0.f || rw != 0.f)) {
    atomicAdd(&sums[0], (double)rl);
    atomicAdd(&sums[1], (double)rw);
  }
}

// ---------------- Kernel E: final combine ----------------------------------
__global__ void kE_final(const double* __restrict__ tl_part, const unsigned int* __restrict__ cnt_part,
                         const double* __restrict__ sums, float* __restrict__ out) {
  __shared__ double sd[256];
  __shared__ unsigned int su[256];
  int t = threadIdx.x;
  double a = 0.0;
  for (int i = t; i < 4096; i += 256) a += tl_part[i];
  sd[t] = a;
  unsigned int c = 0;
  for (int i = t; i < 1024; i += 256) c += cnt_part[i];
  su[t] = c;
  __syncthreads();
  for (int o = 128; o > 0; o >>= 1) {
    if (t < o) { sd[t] += sd[t + o]; su[t] += su[t + o]; }
    __syncthreads();
  }
  if (t == 0) {
    double border = (su[0] > 1u) ? sums[0] * sums[1] : 0.0;
    out[0] = (float)(0.1 * border + sd[0]);
  }
}

extern "C" void kernel_launch(void* const* d_in, const int* in_sizes, int n_in,
                              void* d_out, int out_size, void* d_ws, size_t ws_size,
                              hipStream_t stream) {
  const float* x    = (const float*)d_in[0];
  const float* dist = (const float*)d_in[1];
  const int*   tgt  = (const int*)d_in[2];
  float* out = (float*)d_out;

  char* ws = (char*)d_ws;
  float*        lse      = (float*)(ws + O_LSE);
  float*        klc      = (float*)(ws + O_KLC);
  double*       tl_part  = (double*)(ws + O_TL);
  unsigned int* cnt_part = (unsigned int*)(ws + O_CNT);
  unsigned int* hist     = (unsigned int*)(ws + O_HIST);
  unsigned int* list_n   = (unsigned int*)(ws + O_LISTN);
  double*       sums     = (double*)(ws + O_SUMS);
  float*        eps_fin  = (float*)(ws + O_EPS);
  int*          list     = (int*)(ws + O_LIST);

  hipMemsetAsync(ws + MEMSET_OFF, 0, MEMSET_LEN, stream);

  kA_lse_ce<<<NPIX / 256, 256, 0, stream>>>(x, tgt, lse, tl_part);
  kB_klc<<<NPIX / 256, 256, 0, stream>>>(x, lse, klc, hist);
  kC_eps<<<1, 64, 0, stream>>>(hist, eps_fin);
  kD1_compact<<<NPIX / 1024, 256, 0, stream>>>(klc, eps_fin, list, list_n, cnt_part);
  kD2_border<<<LIST_CAP / 256, 256, 0, stream>>>(x, lse, dist, list, list_n, sums);
  kE_final<<<1, 256, 0, stream>>>(tl_part, cnt_part, sums, out);
}

// Round 4
// 239.725 us; speedup vs baseline: 1.0062x; 1.0062x over previous
//
#include <hip/hip_runtime.h>

// ActiveBoundaryLoss on MI355X.
// d_in[0]=slices f32 (4,19,512,512), d_in[1]=dist_maps f32 (4,1,512,512),
// d_in[2]=targets i32 (4,1,512,512). Output: 1 float scalar.

#define NCLS 19
#define HH 512
#define WW 512
#define HWC (HH*WW)            // 262144
#define CHW (NCLS*HWC)
#define NPIX (4*HWC)           // 1048576
#define NEPS 256
#define MAXDIS 100000.0f
#define LIST_CAP 32768
#define CNT_THRESH 2621u       // continue while count >= 2622
#define SEG 4                  // rows per block in kF

// ws byte offsets
#define O_LSE   0u
#define O_KLC   4194304u
#define O_TL    8388608u           // double tl_part[1024]
#define O_CNT   8421376u           // uint cnt_part[1024]
#define O_HIST  8425472u           // uint hist[257]
#define O_LISTN 8426500u           // uint list_n
#define O_SUMS  8426512u           // double sum_lsce, sum_w
#define O_EPS   8426528u           // float eps_final
#define O_LIST  8426532u           // int list[LIST_CAP]
#define MEMSET_OFF O_HIST
#define MEMSET_LEN 1056u           // hist(1028)+listn(4)+pad(8)+sums(16)

// ---------------- Kernel F: fused lse + CE + klc + eps-histogram ------------
// Grid 1024 = 4(b) x 2(w-half) x 128(row-seg). Block 256 threads = 256 cols.
// Rolling registers: row h+1 (nxt) provides the DOWN neighbor; RIGHT neighbor
// re-loaded (+offR, L1/L2-hit) with its lse recomputed from the same values
// (bit-identical to the neighbor's own lse).
__global__ __launch_bounds__(256, 4) void kF_fused(
    const float* __restrict__ x, const int* __restrict__ tgt,
    float* __restrict__ lse_g, float* __restrict__ klc,
    unsigned int* __restrict__ hist, double* __restrict__ tl_part) {
  __shared__ float eps[NEPS];
  __shared__ unsigned int lh[NEPS + 1];
  __shared__ double sdce[256];
  int tid = threadIdx.x;
  for (int i = tid; i < NEPS + 1; i += 256) lh[i] = 0u;
  if (tid == 0) {
    float e = 1e-5f;
    for (int i = 0; i < NEPS; i++) { eps[i] = e; e *= 1.2f; }  // exact fp32 seq
  }
  __syncthreads();

  int bid = blockIdx.x;
  int b = bid >> 8;
  int r = bid & 255;
  int wh = r >> 7;
  int seg = r & 127;
  int h0 = seg * SEG;
  int w = (wh << 8) + tid;
  const float* xb = x + (size_t)b * CHW + w;   // + h*WW + c*HWC
  int pbase = b * HWC + w;
  bool hasR = (w < WW - 1);
  int offR = hasR ? 1 : 0;

  float cur[NCLS];
  {
    const float* xr0 = xb + h0 * WW;
#pragma unroll
    for (int c = 0; c < NCLS; c++) cur[c] = xr0[(size_t)c * HWC];
  }
  float lse_cur;
  {
    float m = -1e30f;
#pragma unroll
    for (int c = 0; c < NCLS; c++) m = fmaxf(m, cur[c]);
    float s = 0.f;
#pragma unroll
    for (int c = 0; c < NCLS; c++) s += __expf(cur[c] - m);
    lse_cur = m + __logf(s);
  }
  double ce_acc = 0.0;

  for (int h = h0; h < h0 + SEG; ++h) {
    int p = pbase + h * WW;
    int row_n = (h < HH - 1) ? h + 1 : HH - 1;   // clamp: sD dropped at h=511
    const float* xn = xb + row_n * WW;
    float nxt[NCLS];
#pragma unroll
    for (int c = 0; c < NCLS; c++) nxt[c] = xn[(size_t)c * HWC];
    const float* xc_ptr = xb + h * WW;
    float xr[NCLS];
#pragma unroll
    for (int c = 0; c < NCLS; c++) xr[c] = xc_ptr[(size_t)c * HWC + offR];

    // CE for (h,w) while loads are in flight
    int t = tgt[p];
    if (t != 255) {
      float xt = cur[0];
#pragma unroll
      for (int c = 1; c < NCLS; c++) xt = (t == c) ? cur[c] : xt;
      ce_acc += (double)(lse_cur - xt);
    }

    float lse_nxt;
    {
      float m = -1e30f;
#pragma unroll
      for (int c = 0; c < NCLS; c++) m = fmaxf(m, nxt[c]);
      float s = 0.f;
#pragma unroll
      for (int c = 0; c < NCLS; c++) s += __expf(nxt[c] - m);
      lse_nxt = m + __logf(s);
    }
    float lse_r;
    {
      float m = -1e30f;
#pragma unroll
      for (int c = 0; c < NCLS; c++) m = fmaxf(m, xr[c]);
      float s = 0.f;
#pragma unroll
      for (int c = 0; c < NCLS; c++) s += __expf(xr[c] - m);
      lse_r = m + __logf(s);
    }

    bool hasD = (h < HH - 1);
    float sD = 0.f, sR = 0.f;
#pragma unroll
    for (int c = 0; c < NCLS; c++) {
      float lmc = cur[c] - lse_cur;
      float pc = __expf(lmc);
      sD += pc * (lmc - (nxt[c] - lse_nxt));
      sR += pc * (lmc - (xr[c] - lse_r));
    }
    float kv = (hasD ? sD : 0.f) + (hasR ? sR : 0.f);
    klc[p] = kv;
    lse_g[p] = lse_cur;

    // histogram: #{j : kv > eps[j]}
    int lo = 0, hi = NEPS;
    while (lo < hi) {
      int mid = (lo + hi) >> 1;
      if (kv > eps[mid]) lo = mid + 1; else hi = mid;
    }
    atomicAdd(&lh[lo], 1u);

    // roll down
#pragma unroll
    for (int c = 0; c < NCLS; c++) cur[c] = nxt[c];
    lse_cur = lse_nxt;
  }

  sdce[tid] = ce_acc;
  __syncthreads();
  for (int o = 128; o > 0; o >>= 1) {
    if (tid < o) sdce[tid] += sdce[tid + o];
    __syncthreads();
  }
  if (tid == 0) tl_part[bid] = sdce[0];
  for (int i = tid; i < NEPS + 1; i += 256)
    if (lh[i]) atomicAdd(&hist[i], lh[i]);
}

// ---------------- Kernel C: find final eps ---------------------------------
__global__ void kC_eps(const unsigned int* __restrict__ hist, float* __restrict__ eps_final) {
  if (threadIdx.x == 0) {
    unsigned int cnt = 0;
    for (int i = 1; i <= NEPS; i++) cnt += hist[i];
    int K = 0;
    while (cnt > CNT_THRESH && K < NEPS - 1) {
      K++;
      cnt -= hist[K];
    }
    float e = 1e-5f;
    for (int i = 0; i < K; i++) e *= 1.2f;
    *eps_final = e;
  }
}

// ---------------- Kernel D1: dilated mask -> compacted pixel list ----------
__global__ void kD1_compact(const float* __restrict__ klc, const float* __restrict__ epsp,
                            int* __restrict__ list, unsigned int* __restrict__ list_n,
                            unsigned int* __restrict__ cnt_part) {
  __shared__ unsigned int lcnt, lbase;
  __shared__ int lbuf[1024];
  int tid = threadIdx.x;
  if (tid == 0) lcnt = 0u;
  __syncthreads();
  float eps = *epsp;
  int base = blockIdx.x * 1024;
#pragma unroll
  for (int k = 0; k < 4; k++) {
    int p = base + k * 256 + tid;
    int b = p >> 18;
    int hw = p & (HWC - 1);
    int h = hw >> 9;
    int w = hw & 511;
    const float* kb = klc + b * HWC;
    bool pb = false;
#pragma unroll
    for (int dh = -1; dh <= 1; dh++)
#pragma unroll
      for (int dw = -1; dw <= 1; dw++) {
        int hh = h + dh, wn = w + dw;
        if (hh >= 0 && hh < HH && wn >= 0 && wn < WW)
          pb = pb || (kb[hh * WW + wn] > eps);
      }
    if (pb) {
      unsigned int idx = atomicAdd(&lcnt, 1u);
      lbuf[idx] = p;
    }
  }
  __syncthreads();
  if (tid == 0) {
    unsigned int c = lcnt;
    lbase = c ? atomicAdd(list_n, c) : 0u;
    cnt_part[blockIdx.x] = c;
  }
  __syncthreads();
  unsigned int c = lcnt, bo = lbase;
  for (unsigned int j = tid; j < c; j += 256) {
    unsigned int dst = bo + j;
    if (dst < LIST_CAP) list[dst] = lbuf[j];
  }
}

// ---------------- Kernel D2: heavy path, 8 threads per pixel ----------------
// thread = (pixel i, direction k). kl8[k] per-direction in parallel (exact
// c-order per k preserved); leader lane (k==0) does the k-ordered logsumexp.
__global__ void kD2_border(const float* __restrict__ x, const float* __restrict__ lse,
                           const float* __restrict__ dist, const int* __restrict__ list,
                           const unsigned int* __restrict__ list_n,
                           double* __restrict__ sums /* [0]=lsce [1]=w */) {
  const int DXc[9] = {1, -1, 0, 0, -1, 1, -1, 1, 0};
  const int DYc[9] = {0, 0, -1, 1, 1, 1, -1, -1, 0};
  __shared__ float skl[32][8];
  int tid = threadIdx.x;
  int gid = blockIdx.x * 256 + tid;
  int i = gid >> 3, k = gid & 7;
  unsigned int n = *list_n;
  if (n > LIST_CAP) n = LIST_CAP;
  float lsce = 0.f, wv = 0.f;
  bool act = (i < (int)n);
  int g = 8;
  float d8c = 0.f;
  int p = 0, b = 0, h = 0, w = 0, hw = 0;
  if (act) {
    p = list[i];
    b = p >> 18;
    hw = p & (HWC - 1);
    h = hw >> 9;
    w = hw & 511;
    const float* db = dist + b * HWC;
    float dmin = 0.f;
    g = 0;
#pragma unroll
    for (int kk = 0; kk < 9; kk++) {
      int hh = h + DXc[kk], wn = w + DYc[kk];
      float d = (hh >= 0 && hh < HH && wn >= 0 && wn < WW) ? db[hh * WW + wn] : MAXDIS;
      if (kk == 0) { dmin = d; }
      else if (d < dmin) { dmin = d; g = kk; }   // first-min-wins
      if (kk == 8) d8c = d;
    }
    if (g != 8) {
      // dx/dy for this thread's direction k (bit-packed, no scratch array)
      int dx = ((34898 >> (2 * k)) & 3) - 1;   // {1,-1,0,0,-1,1,-1,1}[k]
      int dy = ((2693  >> (2 * k)) & 3) - 1;   // {0,0,-1,1,1,1,-1,-1}[k]
      int hh = min(max(h + dx, 0), HH - 1);
      int wn = min(max(w + dy, 0), WW - 1);
      int hwn = hh * WW + wn;
      const float* xp = x + (size_t)b * CHW;
      float ln = lse[b * HWC + hwn];
      float lc = lse[p];
      float s = 0.f;
#pragma unroll
      for (int c = 0; c < NCLS; c++) {
        float xn = xp[(size_t)c * HWC + hwn];
        float xcv = xp[(size_t)c * HWC + hw];
        float lsn = xn - ln;
        s += __expf(lsn) * (lsn - (xcv - lc));
      }
      skl[tid >> 3][k] = s;
    }
  }
  __syncthreads();
  if (act && g != 8 && k == 0) {
    float kl8[8];
#pragma unroll
    for (int kk = 0; kk < 8; kk++) kl8[kk] = skl[tid >> 3][kk];
    float m8 = kl8[0];
#pragma unroll
    for (int kk = 1; kk < 8; kk++) m8 = fmaxf(m8, kl8[kk]);
    float se = 0.f;
#pragma unroll
    for (int kk = 0; kk < 8; kk++) se += __expf(kl8[kk] - m8);
    float l8 = m8 + __logf(se);
    float sum_lq = 0.f, lq_g = 0.f;
#pragma unroll
    for (int kk = 0; kk < 8; kk++) {
      float lq = kl8[kk] - l8;
      sum_lq += lq;
      if (kk == g) lq_g = lq;
    }
    lsce = -(0.025f * sum_lq + 0.775f * lq_g);
    wv = fminf(d8c, 20.0f) * (1.0f / 20.0f);
  }
  float rl = lsce, rw = wv;
#pragma unroll
  for (int o = 32; o > 0; o >>= 1) {
    rl += __shfl_xor(rl, o);
    rw += __shfl_xor(rw, o);
  }
  if ((threadIdx.x & 63) == 0 && (rl != 0.f || rw != 0.f)) {
    atomicAdd(&sums[0], (double)rl);
    atomicAdd(&sums[1], (double)rw);
  }
}

// ---------------- Kernel E: final combine ----------------------------------
__global__ void kE_final(const double* __restrict__ tl_part, const unsigned int* __restrict__ cnt_part,
                         const double* __restrict__ sums, float* __restrict__ out) {
  __shared__ double sd[256];
  __shared__ unsigned int su[256];
  int t = threadIdx.x;
  double a = 0.0;
  for (int i = t; i < 1024; i += 256) a += tl_part[i];
  sd[t] = a;
  unsigned int c = 0;
  for (int i = t; i < 1024; i += 256) c += cnt_part[i];
  su[t] = c;
  __syncthreads();
  for (int o = 128; o > 0; o >>= 1) {
    if (t < o) { sd[t] += sd[t + o]; su[t] += su[t + o]; }
    __syncthreads();
  }
  if (t == 0) {
    double border = (su[0] > 1u) ? sums[0] * sums[1] : 0.0;
    out[0] = (float)(0.1 * border + sd[0]);
  }
}

extern "C" void kernel_launch(void* const* d_in, const int* in_sizes, int n_in,
                              void* d_out, int out_size, void* d_ws, size_t ws_size,
                              hipStream_t stream) {
  const float* x    = (const float*)d_in[0];
  const float* dist = (const float*)d_in[1];
  const int*   tgt  = (const int*)d_in[2];
  float* out = (float*)d_out;

  char* ws = (char*)d_ws;
  float*        lse      = (float*)(ws + O_LSE);
  float*        klc      = (float*)(ws + O_KLC);
  double*       tl_part  = (double*)(ws + O_TL);
  unsigned int* cnt_part = (unsigned int*)(ws + O_CNT);
  unsigned int* hist     = (unsigned int*)(ws + O_HIST);
  unsigned int* list_n   = (unsigned int*)(ws + O_LISTN);
  double*       sums     = (double*)(ws + O_SUMS);
  float*        eps_fin  = (float*)(ws + O_EPS);
  int*          list     = (int*)(ws + O_LIST);

  hipMemsetAsync(ws + MEMSET_OFF, 0, MEMSET_LEN, stream);

  kF_fused<<<1024, 256, 0, stream>>>(x, tgt, lse, klc, hist, tl_part);
  kC_eps<<<1, 64, 0, stream>>>(hist, eps_fin);
  kD1_compact<<<NPIX / 1024, 256, 0, stream>>>(klc, eps_fin, list, list_n, cnt_part);
  kD2_border<<<(LIST_CAP * 8) / 256, 256, 0, stream>>>(x, lse, dist, list, list_n, sums);
  kE_final<<<1, 256, 0, stream>>>(tl_part, cnt_part, sums, out);
}

// Round 6
// 190.309 us; speedup vs baseline: 1.2674x; 1.2597x over previous
//
#include <hip/hip_runtime.h>

// ActiveBoundaryLoss on MI355X.
// d_in[0]=slices f32 (4,19,512,512), d_in[1]=dist_maps f32 (4,1,512,512),
// d_in[2]=targets i32 (4,1,512,512). Output: 1 float scalar.

#define NCLS 19
#define HH 512
#define WW 512
#define HWC (HH*WW)            // 262144
#define CHW (NCLS*HWC)
#define NPIX (4*HWC)           // 1048576
#define NEPS 256
#define MAXDIS 100000.0f
#define LIST_CAP 32768
#define CNT_THRESH 2621u       // continue while count >= 2622
#define SEG 4                  // rows per block in kF

// ws byte offsets
#define O_LSE   0u
#define O_KLC   4194304u
#define O_TL    8388608u           // double tl_part[1024]
#define O_CNT   8421376u           // uint cnt_part[1024]
#define O_HIST  8425472u           // uint hist[257]
#define O_LISTN 8426500u           // uint list_n
#define O_SUMS  8426512u           // double sum_lsce, sum_w
#define O_EPS   8426528u           // float eps_final
#define O_LIST  8426532u           // int list[LIST_CAP]
#define MEMSET_OFF O_HIST
#define MEMSET_LEN 1056u           // hist(1028)+listn(4)+pad(8)+sums(16)

// ---------------- Kernel F: fused lse + CE + klc + eps-histogram ------------
__global__ __launch_bounds__(256, 4) void kF_fused(
    const float* __restrict__ x, const int* __restrict__ tgt,
    float* __restrict__ lse_g, float* __restrict__ klc,
    unsigned int* __restrict__ hist, double* __restrict__ tl_part) {
  __shared__ float eps[NEPS];
  __shared__ unsigned int lh[NEPS + 1];
  __shared__ double sdce[256];
  int tid = threadIdx.x;
  for (int i = tid; i < NEPS + 1; i += 256) lh[i] = 0u;
  if (tid == 0) {
    float e = 1e-5f;
    for (int i = 0; i < NEPS; i++) { eps[i] = e; e *= 1.2f; }  // exact fp32 seq
  }
  __syncthreads();

  int bid = blockIdx.x;
  int b = bid >> 8;
  int r = bid & 255;
  int wh = r >> 7;
  int seg = r & 127;
  int h0 = seg * SEG;
  int w = (wh << 8) + tid;
  const float* xb = x + (size_t)b * CHW + w;   // + h*WW + c*HWC
  int pbase = b * HWC + w;
  bool hasR = (w < WW - 1);
  int offR = hasR ? 1 : 0;

  float cur[NCLS];
  {
    const float* xr0 = xb + h0 * WW;
#pragma unroll
    for (int c = 0; c < NCLS; c++) cur[c] = xr0[(size_t)c * HWC];
  }
  float lse_cur;
  {
    float m = -1e30f;
#pragma unroll
    for (int c = 0; c < NCLS; c++) m = fmaxf(m, cur[c]);
    float s = 0.f;
#pragma unroll
    for (int c = 0; c < NCLS; c++) s += __expf(cur[c] - m);
    lse_cur = m + __logf(s);
  }
  double ce_acc = 0.0;

  for (int h = h0; h < h0 + SEG; ++h) {
    int p = pbase + h * WW;
    int row_n = (h < HH - 1) ? h + 1 : HH - 1;   // clamp: sD dropped at h=511
    const float* xn = xb + row_n * WW;
    float nxt[NCLS];
#pragma unroll
    for (int c = 0; c < NCLS; c++) nxt[c] = xn[(size_t)c * HWC];
    const float* xc_ptr = xb + h * WW;
    float xr[NCLS];
#pragma unroll
    for (int c = 0; c < NCLS; c++) xr[c] = xc_ptr[(size_t)c * HWC + offR];

    // CE for (h,w) while loads are in flight
    int t = tgt[p];
    if (t != 255) {
      float xt = cur[0];
#pragma unroll
      for (int c = 1; c < NCLS; c++) xt = (t == c) ? cur[c] : xt;
      ce_acc += (double)(lse_cur - xt);
    }

    float lse_nxt;
    {
      float m = -1e30f;
#pragma unroll
      for (int c = 0; c < NCLS; c++) m = fmaxf(m, nxt[c]);
      float s = 0.f;
#pragma unroll
      for (int c = 0; c < NCLS; c++) s += __expf(nxt[c] - m);
      lse_nxt = m + __logf(s);
    }
    float lse_r;
    {
      float m = -1e30f;
#pragma unroll
      for (int c = 0; c < NCLS; c++) m = fmaxf(m, xr[c]);
      float s = 0.f;
#pragma unroll
      for (int c = 0; c < NCLS; c++) s += __expf(xr[c] - m);
      lse_r = m + __logf(s);
    }

    bool hasD = (h < HH - 1);
    float sD = 0.f, sR = 0.f;
#pragma unroll
    for (int c = 0; c < NCLS; c++) {
      float lmc = cur[c] - lse_cur;
      float pc = __expf(lmc);
      sD += pc * (lmc - (nxt[c] - lse_nxt));
      sR += pc * (lmc - (xr[c] - lse_r));
    }
    float kv = (hasD ? sD : 0.f) + (hasR ? sR : 0.f);
    klc[p] = kv;
    lse_g[p] = lse_cur;

    // histogram: #{j : kv > eps[j]}
    int lo = 0, hi = NEPS;
    while (lo < hi) {
      int mid = (lo + hi) >> 1;
      if (kv > eps[mid]) lo = mid + 1; else hi = mid;
    }
    atomicAdd(&lh[lo], 1u);

    // roll down
#pragma unroll
    for (int c = 0; c < NCLS; c++) cur[c] = nxt[c];
    lse_cur = lse_nxt;
  }

  sdce[tid] = ce_acc;
  __syncthreads();
  for (int o = 128; o > 0; o >>= 1) {
    if (tid < o) sdce[tid] += sdce[tid + o];
    __syncthreads();
  }
  if (tid == 0) tl_part[bid] = sdce[0];
  for (int i = tid; i < NEPS + 1; i += 256)
    if (lh[i]) atomicAdd(&hist[i], lh[i]);
}

// ---------------- Kernel C: find final eps ---------------------------------
__global__ void kC_eps(const unsigned int* __restrict__ hist, float* __restrict__ eps_final) {
  if (threadIdx.x == 0) {
    unsigned int cnt = 0;
    for (int i = 1; i <= NEPS; i++) cnt += hist[i];
    int K = 0;
    while (cnt > CNT_THRESH && K < NEPS - 1) {
      K++;
      cnt -= hist[K];
    }
    float e = 1e-5f;
    for (int i = 0; i < K; i++) e *= 1.2f;
    *eps_final = e;
  }
}

// ---------------- Kernel D1: dilated mask -> compacted pixel list ----------
__global__ void kD1_compact(const float* __restrict__ klc, const float* __restrict__ epsp,
                            int* __restrict__ list, unsigned int* __restrict__ list_n,
                            unsigned int* __restrict__ cnt_part) {
  __shared__ unsigned int lcnt, lbase;
  __shared__ int lbuf[1024];
  int tid = threadIdx.x;
  if (tid == 0) lcnt = 0u;
  __syncthreads();
  float eps = *epsp;
  int base = blockIdx.x * 1024;
#pragma unroll
  for (int k = 0; k < 4; k++) {
    int p = base + k * 256 + tid;
    int b = p >> 18;
    int hw = p & (HWC - 1);
    int h = hw >> 9;
    int w = hw & 511;
    const float* kb = klc + b * HWC;
    bool pb = false;
#pragma unroll
    for (int dh = -1; dh <= 1; dh++)
#pragma unroll
      for (int dw = -1; dw <= 1; dw++) {
        int hh = h + dh, wn = w + dw;
        if (hh >= 0 && hh < HH && wn >= 0 && wn < WW)
          pb = pb || (kb[hh * WW + wn] > eps);
      }
    if (pb) {
      unsigned int idx = atomicAdd(&lcnt, 1u);
      lbuf[idx] = p;
    }
  }
  __syncthreads();
  if (tid == 0) {
    unsigned int c = lcnt;
    lbase = c ? atomicAdd(list_n, c) : 0u;
    cnt_part[blockIdx.x] = c;
  }
  __syncthreads();
  unsigned int c = lcnt, bo = lbase;
  for (unsigned int j = tid; j < c; j += 256) {
    unsigned int dst = bo + j;
    if (dst < LIST_CAP) list[dst] = lbuf[j];
  }
}

// ---------------- Kernel D2: heavy path, 8 threads per pixel ----------------
// Latency fix (R4): batch-prefetch dv[9], then xnv[19]+xcv[19] into registers
// BEFORE any dependent math (same c/k order => bit-identical). launch_bounds
// (256,4) caps VGPR at 128 so all 38 class loads stay in flight.
__global__ __launch_bounds__(256, 4) void kD2_border(
    const float* __restrict__ x, const float* __restrict__ lse,
    const float* __restrict__ dist, const int* __restrict__ list,
    const unsigned int* __restrict__ list_n,
    double* __restrict__ sums /* [0]=lsce [1]=w */) {
  const int DXc[9] = {1, -1, 0, 0, -1, 1, -1, 1, 0};
  const int DYc[9] = {0, 0, -1, 1, 1, 1, -1, -1, 0};
  __shared__ float skl[32][8];
  __shared__ float swl[4], sww[4];
  int tid = threadIdx.x;
  int gid = blockIdx.x * 256 + tid;
  int i = gid >> 3, k = gid & 7;
  unsigned int n = *list_n;
  if (n > LIST_CAP) n = LIST_CAP;
  float lsce = 0.f, wv = 0.f;
  bool act = (i < (int)n);
  int g = 8;
  float d8c = 0.f;
  int p = 0, b = 0, h = 0, w = 0, hw = 0;
  if (act) {
    p = list[i];
    b = p >> 18;
    hw = p & (HWC - 1);
    h = hw >> 9;
    w = hw & 511;
    const float* db = dist + b * HWC;
    // prefetch all 9 dist values (independent loads)
    float dv[9];
#pragma unroll
    for (int kk = 0; kk < 9; kk++) {
      int hh = h + DXc[kk], wn = w + DYc[kk];
      dv[kk] = (hh >= 0 && hh < HH && wn >= 0 && wn < WW) ? db[hh * WW + wn] : MAXDIS;
    }
    float dmin = dv[0];
    g = 0;
#pragma unroll
    for (int kk = 1; kk < 9; kk++)
      if (dv[kk] < dmin) { dmin = dv[kk]; g = kk; }   // first-min-wins
    d8c = dv[8];
    if (g != 8) {
      int dx = ((34898 >> (2 * k)) & 3) - 1;   // {1,-1,0,0,-1,1,-1,1}[k]
      int dy = ((2693  >> (2 * k)) & 3) - 1;   // {0,0,-1,1,1,1,-1,-1}[k]
      int hh = min(max(h + dx, 0), HH - 1);
      int wn = min(max(w + dy, 0), WW - 1);
      int hwn = hh * WW + wn;
      const float* xp = x + (size_t)b * CHW;
      float ln = lse[b * HWC + hwn];
      float lc = lse[p];
      // batch prefetch: 38 independent loads, no dependent math in between
      float xnv[NCLS], xcv[NCLS];
#pragma unroll
      for (int c = 0; c < NCLS; c++) xnv[c] = xp[(size_t)c * HWC + hwn];
#pragma unroll
      for (int c = 0; c < NCLS; c++) xcv[c] = xp[(size_t)c * HWC + hw];
      float s = 0.f;
#pragma unroll
      for (int c = 0; c < NCLS; c++) {
        float lsn = xnv[c] - ln;
        s += __expf(lsn) * (lsn - (xcv[c] - lc));
      }
      skl[tid >> 3][k] = s;
    }
  }
  __syncthreads();
  if (act && g != 8 && k == 0) {
    float kl8[8];
#pragma unroll
    for (int kk = 0; kk < 8; kk++) kl8[kk] = skl[tid >> 3][kk];
    float m8 = kl8[0];
#pragma unroll
    for (int kk = 1; kk < 8; kk++) m8 = fmaxf(m8, kl8[kk]);
    float se = 0.f;
#pragma unroll
    for (int kk = 0; kk < 8; kk++) se += __expf(kl8[kk] - m8);
    float l8 = m8 + __logf(se);
    float sum_lq = 0.f, lq_g = 0.f;
#pragma unroll
    for (int kk = 0; kk < 8; kk++) {
      float lq = kl8[kk] - l8;
      sum_lq += lq;
      if (kk == g) lq_g = lq;
    }
    lsce = -(0.025f * sum_lq + 0.775f * lq_g);
    wv = fminf(d8c, 20.0f) * (1.0f / 20.0f);
  }
  // wave reduce -> per-wave LDS slot -> one atomic pair per block
  float rl = lsce, rw = wv;
#pragma unroll
  for (int o = 32; o > 0; o >>= 1) {
    rl += __shfl_xor(rl, o);
    rw += __shfl_xor(rw, o);
  }
  if ((tid & 63) == 0) { swl[tid >> 6] = rl; sww[tid >> 6] = rw; }
  __syncthreads();
  if (tid == 0) {
    float tl = swl[0] + swl[1] + swl[2] + swl[3];
    float tw = sww[0] + sww[1] + sww[2] + sww[3];
    if (tl != 0.f || tw != 0.f) {
      atomicAdd(&sums[0], (double)tl);
      atomicAdd(&sums[1], (double)tw);
    }
  }
}

// ---------------- Kernel E: final combine ----------------------------------
__global__ void kE_final(const double* __restrict__ tl_part, const unsigned int* __restrict__ cnt_part,
                         const double* __restrict__ sums, float* __restrict__ out) {
  __shared__ double sd[256];
  __shared__ unsigned int su[256];
  int t = threadIdx.x;
  double a = 0.0;
  for (int i = t; i < 1024; i += 256) a += tl_part[i];
  sd[t] = a;
  unsigned int c = 0;
  for (int i = t; i < 1024; i += 256) c += cnt_part[i];
  su[t] = c;
  __syncthreads();
  for (int o = 128; o > 0; o >>= 1) {
    if (t < o) { sd[t] += sd[t + o]; su[t] += su[t + o]; }
    __syncthreads();
  }
  if (t == 0) {
    double border = (su[0] > 1u) ? sums[0] * sums[1] : 0.0;
    out[0] = (float)(0.1 * border + sd[0]);
  }
}

extern "C" void kernel_launch(void* const* d_in, const int* in_sizes, int n_in,
                              void* d_out, int out_size, void* d_ws, size_t ws_size,
                              hipStream_t stream) {
  const float* x    = (const float*)d_in[0];
  const float* dist = (const float*)d_in[1];
  const int*   tgt  = (const int*)d_in[2];
  float* out = (float*)d_out;

  char* ws = (char*)d_ws;
  float*        lse      = (float*)(ws + O_LSE);
  float*        klc      = (float*)(ws + O_KLC);
  double*       tl_part  = (double*)(ws + O_TL);
  unsigned int* cnt_part = (unsigned int*)(ws + O_CNT);
  unsigned int* hist     = (unsigned int*)(ws + O_HIST);
  unsigned int* list_n   = (unsigned int*)(ws + O_LISTN);
  double*       sums     = (double*)(ws + O_SUMS);
  float*        eps_fin  = (float*)(ws + O_EPS);
  int*          list     = (int*)(ws + O_LIST);

  hipMemsetAsync(ws + MEMSET_OFF, 0, MEMSET_LEN, stream);

  kF_fused<<<1024, 256, 0, stream>>>(x, tgt, lse, klc, hist, tl_part);
  kC_eps<<<1, 64, 0, stream>>>(hist, eps_fin);
  kD1_compact<<<NPIX / 1024, 256, 0, stream>>>(klc, eps_fin, list, list_n, cnt_part);
  kD2_border<<<(LIST_CAP * 8) / 256, 256, 0, stream>>>(x, lse, dist, list, list_n, sums);
  kE_final<<<1, 256, 0, stream>>>(tl_part, cnt_part, sums, out);
}